// Round 1
// baseline (1329.737 us; speedup 1.0000x reference)
//
#include <hip/hip_runtime.h>
#include <hip/hip_bf16.h>
#include <stdint.h>
#include <stddef.h>

#define T_STEPS 28
#define I_DIM 28
#define H_DIM 64
#define O_DIM 10
#define BT 32    // batch rows per block
#define NTHREADS 256

typedef short bf16x8  __attribute__((ext_vector_type(8)));
typedef float f32x4   __attribute__((ext_vector_type(4)));
typedef float f32x2   __attribute__((ext_vector_type(2)));

// exp2 scale constants folded into weights:
//   sigmoid(z) = rcp(1 + exp2(-log2e * z))      -> scale i,f,o rows by KS
//   tanh(z)    = 1 - 2*rcp(1 + exp2(2*log2e*z)) -> scale g rows by KG
#define KS (-1.4426950408889634f)
#define KG ( 2.8853900817779268f)

__device__ __forceinline__ short f2bf(float f){
    uint32_t u = __builtin_bit_cast(uint32_t, f);
    u = (u + 0x7fffu + ((u >> 16) & 1u)) >> 16;
    return (short)u;
}
__device__ __forceinline__ float bf2f(short v){
    return __builtin_bit_cast(float, (uint32_t)(uint16_t)v << 16);
}
__device__ __forceinline__ uint32_t pack_bf16x2(float lo, float hi){
    float2 p2; p2.x = lo; p2.y = hi;
    __hip_bfloat162 p = __float22bfloat162_rn(p2);
    uint32_t u;
    __builtin_memcpy(&u, &p, 4);
    return u;
}

// LDS layout (bytes):
//   x0: short[32][40] @ 0      (2560)
//   x1: short[32][40] @ 2560   (2560)
//   h0: short[32][76] @ 5120   (4864)   (stride 76: quads land on distinct bank
//   h1: short[32][76] @ 9984   (4864)    groups for the b16 h-stores; 72 aliased 4-way)
//   wout_t: float[640] @ 14848 (2560)
//   bout_s: float[12]  @ 17408 (48)
#define X_OFF(b)  ((b) * 2560)
#define H_OFF(b)  (5120 + (b) * 4864)
#define H_STRIDE  76
#define SMEM_BYTES (17408 + 48)

__global__ __launch_bounds__(NTHREADS, 8)
void lstm_fused(const float* __restrict__ x,
                const float* __restrict__ W_ih,
                const float* __restrict__ W_hh,
                const float* __restrict__ b_ih,
                const float* __restrict__ b_hh,
                const float* __restrict__ W_out,
                const float* __restrict__ b_out,
                float* __restrict__ out)
{
    __shared__ alignas(16) unsigned char smem[SMEM_BYTES];
    float* wout_t = (float*)(smem + 14848);
    float* bout_s = (float*)(smem + 17408);

    const int tid    = threadIdx.x;
    const int w      = tid >> 6;      // wave 0..3
    const int jgroup = w;             // hidden-col tile: j in [16*jgroup, 16*jgroup+16)
    const int lane = tid & 63;
    const int col  = lane & 15;
    const int quad = lane >> 4;
    const int jcol = jgroup * 16 + col;
    const int b0   = blockIdx.x * BT;

    // ---- weight B-fragments in registers, pre-scaled by exp2 constants ----
    // B[k][n]: lane holds n = nt*64 + jgroup*16 + col, k = quad*8 + j
    bf16x8 wih[4];
    bf16x8 whh[2][4];
    f32x4  bias4[4];           // replicated bias -> direct C operand of first MFMA
    #pragma unroll
    for (int nt = 0; nt < 4; ++nt){
        const float sc = (nt == 2) ? KG : KS;
        const int n = nt * 64 + jgroup * 16 + col;
        #pragma unroll
        for (int j = 0; j < 8; ++j){
            const int k = quad * 8 + j;
            wih[nt][j] = (k < I_DIM) ? f2bf(sc * W_ih[n * I_DIM + k]) : (short)0;
        }
        #pragma unroll
        for (int s = 0; s < 2; ++s)
            #pragma unroll
            for (int j = 0; j < 8; ++j){
                const int k = s * 32 + quad * 8 + j;
                whh[s][nt][j] = f2bf(sc * W_hh[n * H_DIM + k]);
            }
        const float b = sc * (b_ih[n] + b_hh[n]);
        f32x4 bv; bv[0] = b; bv[1] = b; bv[2] = b; bv[3] = b;
        bias4[nt] = bv;
    }

    // ---- stage W_out (transposed) + b_out ----
    for (int idx = tid; idx < H_DIM * O_DIM; idx += NTHREADS){
        const int j = idx / O_DIM;
        const int o = idx - j * O_DIM;
        wout_t[idx] = W_out[o * H_DIM + j];
    }
    if (tid < O_DIM) bout_s[tid] = b_out[tid];

    // ---- zero h buffer 0 (initial state) ----
    for (int idx = tid; idx < BT * H_STRIDE; idx += NTHREADS)
        ((short*)(smem + H_OFF(0)))[idx] = 0;

    // ---- x staging: 8 threads per row, 4 cols each (cols 28..31 write zeros) ----
    const int row = tid >> 3;         // 0..31
    const int seg = tid & 7;
    const float* pxs = x + (size_t)(b0 + row) * (T_STEPS * I_DIM) + seg * 4;

    float xa[4];
    #pragma unroll
    for (int u = 0; u < 4; ++u)
        xa[u] = (seg * 4 + u < I_DIM) ? pxs[u] : 0.0f;   // seg 7 pad stays 0 forever
    pxs += I_DIM;

    float cst[2][4];
    #pragma unroll
    for (int m = 0; m < 2; ++m)
        #pragma unroll
        for (int r = 0; r < 4; ++r) cst[m][r] = 0.0f;

    #pragma unroll 2
    for (int t = 0; t < T_STEPS; ++t){
        short (*xb)[40] = (short(*)[40])(smem + X_OFF(t & 1));
        // stage x(t): packed cvt + one b64 LDS store
        {
            uint2 v;
            v.x = pack_bf16x2(xa[0], xa[1]);
            v.y = pack_bf16x2(xa[2], xa[3]);
            *(uint2*)&xb[row][seg * 4] = v;
        }
        __syncthreads();   // single barrier per step; covers x(t) and h(t) writes

        // prefetch x(t+1) AFTER the barrier: stays in flight across compute
        if (t < T_STEPS - 1){
            #pragma unroll
            for (int u = 0; u < 4; ++u)
                if (seg * 4 + u < I_DIM) xa[u] = pxs[u];
            pxs += I_DIM;
        }

        const short (*hr)[H_STRIDE] = (const short(*)[H_STRIDE])(smem + H_OFF(t & 1));
        short (*hw)[H_STRIDE]       = (short(*)[H_STRIDE])(smem + H_OFF((t + 1) & 1));

        #pragma unroll
        for (int m = 0; m < 2; ++m){
            const int mt = m;

            // x-projection with bias as the C operand (no acc-init movs)
            f32x4 acc[4];
            {
                bf16x8 a = *(const bf16x8*)&xb[mt * 16 + col][quad * 8];
                #pragma unroll
                for (int nt = 0; nt < 4; ++nt)
                    acc[nt] = __builtin_amdgcn_mfma_f32_16x16x32_bf16(a, wih[nt], bias4[nt], 0, 0, 0);
            }
            // recurrence
            #pragma unroll
            for (int s = 0; s < 2; ++s){
                bf16x8 a = *(const bf16x8*)&hr[mt * 16 + col][s * 32 + quad * 8];
                #pragma unroll
                for (int nt = 0; nt < 4; ++nt)
                    acc[nt] = __builtin_amdgcn_mfma_f32_16x16x32_bf16(a, whh[s][nt], acc[nt], 0, 0, 0);
            }

            // activations: paired reciprocals (one rcp serves two sigmoids),
            // float2 lanes to pick up v_pk_{add,mul,fma}_f32.
            //   i = 1/DA, f = 1/DB  via R1 = rcp(DA*DB):  i = R1*DB, f = R1*DA
            //   o = 1/DO, 1/DG      via R2 = rcp(DG*DO):  o = R2*DG, g = 1-2*R2*DO
            //   tanh(c) paired across adjacent rows: R5 = rcp(D5a*D5b)
            // Overflow: pair products <= 2^88 (gates); tanh pair inf -> rcp=0 ->
            // tanh=1 which is the correct saturated limit (D5 always finite, |c|<=28).
            float hv[4];
            #pragma unroll
            for (int p = 0; p < 2; ++p){
                const int r0 = 2 * p, r1 = 2 * p + 1;
                f32x2 EA, EB, EG, EO;
                EA[0] = __builtin_amdgcn_exp2f(acc[0][r0]); EA[1] = __builtin_amdgcn_exp2f(acc[0][r1]);
                EB[0] = __builtin_amdgcn_exp2f(acc[1][r0]); EB[1] = __builtin_amdgcn_exp2f(acc[1][r1]);
                EG[0] = __builtin_amdgcn_exp2f(acc[2][r0]); EG[1] = __builtin_amdgcn_exp2f(acc[2][r1]);
                EO[0] = __builtin_amdgcn_exp2f(acc[3][r0]); EO[1] = __builtin_amdgcn_exp2f(acc[3][r1]);
                const f32x2 one = {1.0f, 1.0f};
                const f32x2 DA = one + EA, DB = one + EB, DG = one + EG, DO = one + EO;
                const f32x2 pAB = DA * DB, pGO = DG * DO;
                f32x2 R1, R2;
                R1[0] = __builtin_amdgcn_rcpf(pAB[0]); R1[1] = __builtin_amdgcn_rcpf(pAB[1]);
                R2[0] = __builtin_amdgcn_rcpf(pGO[0]); R2[1] = __builtin_amdgcn_rcpf(pGO[1]);
                const f32x2 iv = R1 * DB;
                const f32x2 fv = R1 * DA;
                const f32x2 ov = R2 * DG;
                const f32x2 gv = one - 2.0f * (R2 * DO);
                const f32x2 cold = {cst[m][r0], cst[m][r1]};
                const f32x2 cnew = fv * cold + iv * gv;
                cst[m][r0] = cnew[0]; cst[m][r1] = cnew[1];
                f32x2 E5;
                E5[0] = __builtin_amdgcn_exp2f(KG * cnew[0]);
                E5[1] = __builtin_amdgcn_exp2f(KG * cnew[1]);
                const f32x2 D5 = one + E5;
                const float R5 = __builtin_amdgcn_rcpf(D5[0] * D5[1]);
                const f32x2 sw = {D5[1], D5[0]};
                const f32x2 th = one - (2.0f * R5) * sw;
                const f32x2 hv2 = ov * th;
                hv[r0] = hv2[0]; hv[r1] = hv2[1];
            }
            // packed conversion, two b16 stores per pair (rows differ by 1)
            #pragma unroll
            for (int rp = 0; rp < 2; ++rp){
                uint32_t u = pack_bf16x2(hv[2 * rp], hv[2 * rp + 1]);
                hw[mt * 16 + quad * 4 + 2 * rp    ][jcol] = (short)(u & 0xffffu);
                hw[mt * 16 + quad * 4 + 2 * rp + 1][jcol] = (short)(u >> 16);
            }
        }
    }
    __syncthreads();

    // ---- output projection from final h (bf16, in h buffer 0) ----
    const short (*hfin)[H_STRIDE] = (const short(*)[H_STRIDE])(smem + H_OFF(0));
    for (int idx = tid; idx < BT * O_DIM; idx += NTHREADS){
        const int m = idx / O_DIM;
        const int o = idx - m * O_DIM;
        float s = bout_s[o];
        #pragma unroll 8
        for (int j = 0; j < H_DIM; ++j)
            s += bf2f(hfin[m][j]) * wout_t[j * O_DIM + o];
        out[(size_t)b0 * O_DIM + idx] = s;
    }
}

extern "C" void kernel_launch(void* const* d_in, const int* in_sizes, int n_in,
                              void* d_out, int out_size, void* d_ws, size_t ws_size,
                              hipStream_t stream) {
    const float* x     = (const float*)d_in[0];
    const float* W_ih  = (const float*)d_in[1];
    const float* W_hh  = (const float*)d_in[2];
    const float* b_ih  = (const float*)d_in[3];
    const float* b_hh  = (const float*)d_in[4];
    const float* W_out = (const float*)d_in[5];
    const float* b_out = (const float*)d_in[6];
    float* out = (float*)d_out;

    const int grid = 65536 / BT;   // 2048 blocks x 256 threads
    lstm_fused<<<grid, NTHREADS, 0, stream>>>(x, W_ih, W_hh, b_ih, b_hh, W_out, b_out, out);
}

// Round 2
// 387.443 us; speedup vs baseline: 3.4321x; 3.4321x over previous
//
#include <hip/hip_runtime.h>
#include <hip/hip_bf16.h>
#include <stdint.h>
#include <stddef.h>

#define T_STEPS 28
#define I_DIM 28
#define H_DIM 64
#define O_DIM 10
#define BT 64    // batch rows per block
#define NTHREADS 512

typedef short bf16x8  __attribute__((ext_vector_type(8)));
typedef float f32x4   __attribute__((ext_vector_type(4)));
typedef float f32x2   __attribute__((ext_vector_type(2)));

// exp2 scale constants folded into weights:
//   sigmoid(z) = rcp(1 + exp2(-log2e * z))      -> scale i,f,o rows by KS
//   tanh(z)    = 1 - 2*rcp(1 + exp2(2*log2e*z)) -> scale g rows by KG
#define KS (-1.4426950408889634f)
#define KG ( 2.8853900817779268f)

__device__ __forceinline__ short f2bf(float f){
    uint32_t u = __builtin_bit_cast(uint32_t, f);
    u = (u + 0x7fffu + ((u >> 16) & 1u)) >> 16;
    return (short)u;
}
__device__ __forceinline__ float bf2f(short v){
    return __builtin_bit_cast(float, (uint32_t)(uint16_t)v << 16);
}
// packed f32x2 -> bf16x2 (RNE) as raw bits
__device__ __forceinline__ uint32_t pack_bf16x2(float lo, float hi){
    float2 p2; p2.x = lo; p2.y = hi;
    __hip_bfloat162 p = __float22bfloat162_rn(p2);
    uint32_t u;
    __builtin_memcpy(&u, &p, 4);
    return u;
}

// LDS layout (bytes):
//   x0: short[64][40] @ 0      (5120)
//   x1: short[64][40] @ 5120   (5120)
//   h0: short[64][72] @ 10240  (9216)  (final h lands here after 28 steps)
//   h1: short[64][72] @ 19456  (9216)
//   wout_t: float[640] @ 28672 (2560)
//   bout_s: float[12]  @ 31232 (48)
// stride 72 shorts = 144 B keeps every row 16B-aligned -> ds_read_b128;
// bank conflicts at this stride are ~1% of SIMD cycles (measured), not worth
// breaking b128 alignment for.
#define X_OFF(b)  ((b) * 5120)
#define H_OFF(b)  (10240 + (b) * 9216)
#define SMEM_BYTES (31232 + 48)

__global__ __launch_bounds__(NTHREADS, 4)
void lstm_fused(const float* __restrict__ x,
                const float* __restrict__ W_ih,
                const float* __restrict__ W_hh,
                const float* __restrict__ b_ih,
                const float* __restrict__ b_hh,
                const float* __restrict__ W_out,
                const float* __restrict__ b_out,
                float* __restrict__ out)
{
    __shared__ alignas(16) unsigned char smem[SMEM_BYTES];
    float* wout_t = (float*)(smem + 28672);
    float* bout_s = (float*)(smem + 31232);

    const int tid    = threadIdx.x;
    const int w      = tid >> 6;      // wave 0..7
    const int jgroup = w & 3;         // hidden-col tile: j in [16*jgroup, 16*jgroup+16)
    const int mgroup = w >> 2;        // m-tile pair: mt in {2*mgroup, 2*mgroup+1}
    const int lane = tid & 63;
    const int col  = lane & 15;
    const int quad = lane >> 4;
    const int jcol = jgroup * 16 + col;
    const int b0   = blockIdx.x * BT;

    // ---- weight B-fragments in registers, pre-scaled by exp2 constants ----
    // B[k][n]: lane holds n = nt*64 + jgroup*16 + col, k = quad*8 + j
    bf16x8 wih[4];
    bf16x8 whh[2][4];
    f32x4  bias4[4];           // replicated bias -> direct C operand of first MFMA
    #pragma unroll
    for (int nt = 0; nt < 4; ++nt){
        const float sc = (nt == 2) ? KG : KS;
        const int n = nt * 64 + jgroup * 16 + col;
        #pragma unroll
        for (int j = 0; j < 8; ++j){
            const int k = quad * 8 + j;
            wih[nt][j] = (k < I_DIM) ? f2bf(sc * W_ih[n * I_DIM + k]) : (short)0;
        }
        #pragma unroll
        for (int s = 0; s < 2; ++s)
            #pragma unroll
            for (int j = 0; j < 8; ++j){
                const int k = s * 32 + quad * 8 + j;
                whh[s][nt][j] = f2bf(sc * W_hh[n * H_DIM + k]);
            }
        const float b = sc * (b_ih[n] + b_hh[n]);
        f32x4 bv; bv[0] = b; bv[1] = b; bv[2] = b; bv[3] = b;
        bias4[nt] = bv;
    }

    // ---- stage W_out (transposed) + b_out ----
    for (int idx = tid; idx < H_DIM * O_DIM; idx += NTHREADS){
        const int j = idx / O_DIM;
        const int o = idx - j * O_DIM;
        wout_t[idx] = W_out[o * H_DIM + j];
    }
    if (tid < O_DIM) bout_s[tid] = b_out[tid];

    // ---- zero h buffer 0 (initial state) ----
    for (int idx = tid; idx < 64 * 72; idx += NTHREADS)
        ((short*)(smem + H_OFF(0)))[idx] = 0;

    // ---- x staging: 8 threads per row, 4 cols each (cols 28..31 write zeros) ----
    const int row = tid >> 3;
    const int seg = tid & 7;
    const float* pxs = x + (size_t)(b0 + row) * (T_STEPS * I_DIM) + seg * 4;

    float xa[4];
    #pragma unroll
    for (int u = 0; u < 4; ++u)
        xa[u] = (seg * 4 + u < I_DIM) ? pxs[u] : 0.0f;   // seg 7 pad stays 0 forever
    pxs += I_DIM;

    float cst[2][4];
    #pragma unroll
    for (int m = 0; m < 2; ++m)
        #pragma unroll
        for (int r = 0; r < 4; ++r) cst[m][r] = 0.0f;

    for (int t = 0; t < T_STEPS; ++t){
        short (*xb)[40] = (short(*)[40])(smem + X_OFF(t & 1));
        // stage x(t): packed cvt + one b64 LDS store
        {
            uint2 v;
            v.x = pack_bf16x2(xa[0], xa[1]);
            v.y = pack_bf16x2(xa[2], xa[3]);
            *(uint2*)&xb[row][seg * 4] = v;
        }
        __syncthreads();   // single barrier per step; no vmcnt pending here

        // prefetch x(t+1) AFTER the barrier: stays in flight across compute
        if (t < T_STEPS - 1){
            #pragma unroll
            for (int u = 0; u < 4; ++u)
                if (seg * 4 + u < I_DIM) xa[u] = pxs[u];
            pxs += I_DIM;
        }

        const short (*hr)[72] = (const short(*)[72])(smem + H_OFF(t & 1));
        short (*hw)[72]       = (short(*)[72])(smem + H_OFF((t + 1) & 1));

        #pragma unroll
        for (int m = 0; m < 2; ++m){
            const int mt = mgroup * 2 + m;

            // x-projection with bias as the C operand (no acc-init movs)
            f32x4 acc[4];
            {
                bf16x8 a = *(const bf16x8*)&xb[mt * 16 + col][quad * 8];
                #pragma unroll
                for (int nt = 0; nt < 4; ++nt)
                    acc[nt] = __builtin_amdgcn_mfma_f32_16x16x32_bf16(a, wih[nt], bias4[nt], 0, 0, 0);
            }
            // recurrence
            #pragma unroll
            for (int s = 0; s < 2; ++s){
                bf16x8 a = *(const bf16x8*)&hr[mt * 16 + col][s * 32 + quad * 8];
                #pragma unroll
                for (int nt = 0; nt < 4; ++nt)
                    acc[nt] = __builtin_amdgcn_mfma_f32_16x16x32_bf16(a, whh[s][nt], acc[nt], 0, 0, 0);
            }

            // activations: paired reciprocals -- one v_rcp serves two sigmoids.
            //   i = 1/DA, f = 1/DB  via R1 = rcp(DA*DB):  i = R1*DB, f = R1*DA
            //   o = 1/DO, g via R2 = rcp(DG*DO):          o = R2*DG, g = 1-2*R2*DO
            //   tanh(c) paired across adjacent rows:      R5 = rcp(D5a*D5b)
            // Trans count/elem: 5 exp2 + 2.5 rcp (was 5+5). f32x2 lanes pick up
            // v_pk_{add,mul,fma}_f32 for the extra muls.
            // Overflow: |gate preact| << 2^42 so pair products finite; tanh pair
            // inf only when both cells saturated -> rcp=0 -> tanh=1 (correct limit).
            float hv[4];
            #pragma unroll
            for (int p = 0; p < 2; ++p){
                const int r0 = 2 * p, r1 = 2 * p + 1;
                const f32x2 one = {1.0f, 1.0f};
                // sigmoid(i), sigmoid(f) share one rcp
                f32x2 DA, DB;
                DA[0] = __builtin_amdgcn_exp2f(acc[0][r0]); DA[1] = __builtin_amdgcn_exp2f(acc[0][r1]);
                DB[0] = __builtin_amdgcn_exp2f(acc[1][r0]); DB[1] = __builtin_amdgcn_exp2f(acc[1][r1]);
                DA = one + DA; DB = one + DB;
                const f32x2 pAB = DA * DB;
                f32x2 R1;
                R1[0] = __builtin_amdgcn_rcpf(pAB[0]); R1[1] = __builtin_amdgcn_rcpf(pAB[1]);
                const f32x2 iv = R1 * DB;
                const f32x2 fv = R1 * DA;             // DA,DB dead
                // tanh(g), sigmoid(o) share one rcp
                f32x2 DG, DO;
                DG[0] = __builtin_amdgcn_exp2f(acc[2][r0]); DG[1] = __builtin_amdgcn_exp2f(acc[2][r1]);
                DO[0] = __builtin_amdgcn_exp2f(acc[3][r0]); DO[1] = __builtin_amdgcn_exp2f(acc[3][r1]);
                DG = one + DG; DO = one + DO;
                const f32x2 pGO = DG * DO;
                f32x2 R2;
                R2[0] = __builtin_amdgcn_rcpf(pGO[0]); R2[1] = __builtin_amdgcn_rcpf(pGO[1]);
                const f32x2 ov = R2 * DG;
                const f32x2 gv = one - 2.0f * (R2 * DO);   // DG,DO dead
                // cell update
                const f32x2 cold = {cst[m][r0], cst[m][r1]};
                const f32x2 cnew = fv * cold + iv * gv;
                cst[m][r0] = cnew[0]; cst[m][r1] = cnew[1];
                // tanh(c) for both rows via one rcp
                f32x2 D5;
                D5[0] = __builtin_amdgcn_exp2f(KG * cnew[0]);
                D5[1] = __builtin_amdgcn_exp2f(KG * cnew[1]);
                D5 = one + D5;
                const float R5 = __builtin_amdgcn_rcpf(D5[0] * D5[1]);
                const f32x2 sw = {D5[1], D5[0]};
                const f32x2 th = one - (2.0f * R5) * sw;
                const f32x2 hv2 = ov * th;
                hv[r0] = hv2[0]; hv[r1] = hv2[1];
            }
            // packed conversion, two b16 stores per pair (rows differ by 1)
            #pragma unroll
            for (int rp = 0; rp < 2; ++rp){
                uint32_t u = pack_bf16x2(hv[2 * rp], hv[2 * rp + 1]);
                hw[mt * 16 + quad * 4 + 2 * rp    ][jcol] = (short)(u & 0xffffu);
                hw[mt * 16 + quad * 4 + 2 * rp + 1][jcol] = (short)(u >> 16);
            }
        }
    }
    __syncthreads();

    // ---- output projection from final h (bf16, in h buffer 0) ----
    const short (*hfin)[72] = (const short(*)[72])(smem + H_OFF(0));
    for (int idx = tid; idx < BT * O_DIM; idx += NTHREADS){
        const int m = idx / O_DIM;
        const int o = idx - m * O_DIM;
        float s = bout_s[o];
        #pragma unroll 8
        for (int j = 0; j < H_DIM; ++j)
            s += bf2f(hfin[m][j]) * wout_t[j * O_DIM + o];
        out[(size_t)b0 * O_DIM + idx] = s;
    }
}

extern "C" void kernel_launch(void* const* d_in, const int* in_sizes, int n_in,
                              void* d_out, int out_size, void* d_ws, size_t ws_size,
                              hipStream_t stream) {
    const float* x     = (const float*)d_in[0];
    const float* W_ih  = (const float*)d_in[1];
    const float* W_hh  = (const float*)d_in[2];
    const float* b_ih  = (const float*)d_in[3];
    const float* b_hh  = (const float*)d_in[4];
    const float* W_out = (const float*)d_in[5];
    const float* b_out = (const float*)d_in[6];
    float* out = (float*)d_out;

    const int grid = 65536 / BT;   // 1024 blocks x 512 threads
    lstm_fused<<<grid, NTHREADS, 0, stream>>>(x, W_ih, W_hh, b_ih, b_hh, W_out, b_out, out);
}

// Round 3
// 373.310 us; speedup vs baseline: 3.5620x; 1.0379x over previous
//
#include <hip/hip_runtime.h>
#include <hip/hip_bf16.h>
#include <stdint.h>
#include <stddef.h>

#define T_STEPS 28
#define I_DIM 28
#define H_DIM 64
#define O_DIM 10
#define BT 32    // batch rows per block
#define NTHREADS 256   // 4 waves: small barrier group, 4 independent groups/CU

typedef short bf16x8  __attribute__((ext_vector_type(8)));
typedef float f32x4   __attribute__((ext_vector_type(4)));

// exp2 scale constants folded into weights:
//   sigmoid(z) = rcp(1 + exp2(-log2e * z))      -> scale i,f,o rows by KS
//   tanh(z)    = 1 - 2*rcp(1 + exp2(2*log2e*z)) -> scale g rows by KG
#define KS (-1.4426950408889634f)
#define KG ( 2.8853900817779268f)

__device__ __forceinline__ short f2bf(float f){
    uint32_t u = __builtin_bit_cast(uint32_t, f);
    u = (u + 0x7fffu + ((u >> 16) & 1u)) >> 16;
    return (short)u;
}
__device__ __forceinline__ float bf2f(short v){
    return __builtin_bit_cast(float, (uint32_t)(uint16_t)v << 16);
}
// packed f32x2 -> bf16x2 (RNE) as raw bits
__device__ __forceinline__ uint32_t pack_bf16x2(float lo, float hi){
    float2 p2; p2.x = lo; p2.y = hi;
    __hip_bfloat162 p = __float22bfloat162_rn(p2);
    uint32_t u;
    __builtin_memcpy(&u, &p, 4);
    return u;
}

// LDS layout (bytes), BT=32:
//   x0: short[32][40] @ 0      (2560)
//   x1: short[32][40] @ 2560   (2560)
//   h0: short[32][72] @ 5120   (4608)  (final h lands here after 28 steps)
//   h1: short[32][72] @ 9728   (4608)
//   wout_t: float[640] @ 14336 (2560)
//   bout_s: float[12]  @ 16896 (48)
// stride 72 shorts = 144 B keeps every row 16B-aligned -> ds_read_b128.
#define X_OFF(b)  ((b) * 2560)
#define H_OFF(b)  (5120 + (b) * 4608)
#define SMEM_BYTES (16896 + 48)

__global__ __launch_bounds__(NTHREADS, 4)   // 4 waves/EU -> 4 blocks/CU, 128-reg cap
void lstm_fused(const float* __restrict__ x,
                const float* __restrict__ W_ih,
                const float* __restrict__ W_hh,
                const float* __restrict__ b_ih,
                const float* __restrict__ b_hh,
                const float* __restrict__ W_out,
                const float* __restrict__ b_out,
                float* __restrict__ out)
{
    __shared__ alignas(16) unsigned char smem[SMEM_BYTES];
    float* wout_t = (float*)(smem + 14336);
    float* bout_s = (float*)(smem + 16896);

    const int tid    = threadIdx.x;
    const int w      = tid >> 6;      // wave 0..3
    const int jgroup = w;             // hidden-col tile: j in [16*jgroup, 16*jgroup+16)
    const int lane = tid & 63;
    const int col  = lane & 15;
    const int quad = lane >> 4;
    const int jcol = jgroup * 16 + col;
    const int b0   = blockIdx.x * BT;

    // ---- weight B-fragments in registers, pre-scaled by exp2 constants ----
    // B[k][n]: lane holds n = nt*64 + jgroup*16 + col, k = quad*8 + j
    // Bias folded into wih row k == I_DIM (x pad col 28 is constant 1.0).
    bf16x8 wih[4];
    bf16x8 whh[2][4];
    #pragma unroll
    for (int nt = 0; nt < 4; ++nt){
        const float sc = (nt == 2) ? KG : KS;
        const int n = nt * 64 + jgroup * 16 + col;
        #pragma unroll
        for (int j = 0; j < 8; ++j){
            const int k = quad * 8 + j;
            wih[nt][j] = (k < I_DIM) ? f2bf(sc * W_ih[n * I_DIM + k])
                       : (k == I_DIM) ? f2bf(sc * (b_ih[n] + b_hh[n]))
                       : (short)0;
        }
        #pragma unroll
        for (int s = 0; s < 2; ++s)
            #pragma unroll
            for (int j = 0; j < 8; ++j){
                const int k = s * 32 + quad * 8 + j;
                whh[s][nt][j] = f2bf(sc * W_hh[n * H_DIM + k]);
            }
    }
    const f32x4 z4 = {0.0f, 0.0f, 0.0f, 0.0f};

    // ---- stage W_out (transposed) + b_out ----
    for (int idx = tid; idx < H_DIM * O_DIM; idx += NTHREADS){
        const int j = idx / O_DIM;
        const int o = idx - j * O_DIM;
        wout_t[idx] = W_out[o * H_DIM + j];
    }
    if (tid < O_DIM) bout_s[tid] = b_out[tid];

    // ---- zero h buffer 0 (initial state) ----
    for (int idx = tid; idx < BT * 72; idx += NTHREADS)
        ((short*)(smem + H_OFF(0)))[idx] = 0;

    // ---- x staging: 8 threads per row, 4 cols each ----
    // col 28 (seg 7, u 0) carries the constant 1.0 that multiplies the folded
    // bias row of wih; cols 29..31 stay 0. Prefetch only overwrites u with
    // global col < I_DIM, so the pad values persist across steps.
    const int row = tid >> 3;          // 0..31
    const int seg = tid & 7;
    const float* pxs = x + (size_t)(b0 + row) * (T_STEPS * I_DIM) + seg * 4;

    float xa[4];
    #pragma unroll
    for (int u = 0; u < 4; ++u){
        const int c = seg * 4 + u;
        xa[u] = (c < I_DIM) ? pxs[u] : (c == I_DIM ? 1.0f : 0.0f);
    }
    pxs += I_DIM;

    float cst[2][4];
    #pragma unroll
    for (int m = 0; m < 2; ++m)
        #pragma unroll
        for (int r = 0; r < 4; ++r) cst[m][r] = 0.0f;

    for (int t = 0; t < T_STEPS; ++t){
        short (*xb)[40] = (short(*)[40])(smem + X_OFF(t & 1));
        // stage x(t): packed cvt + one b64 LDS store
        {
            uint2 v;
            v.x = pack_bf16x2(xa[0], xa[1]);
            v.y = pack_bf16x2(xa[2], xa[3]);
            *(uint2*)&xb[row][seg * 4] = v;
        }
        __syncthreads();   // single barrier per step; no vmcnt pending here

        // prefetch x(t+1) AFTER the barrier: stays in flight across compute
        if (t < T_STEPS - 1){
            #pragma unroll
            for (int u = 0; u < 4; ++u)
                if (seg * 4 + u < I_DIM) xa[u] = pxs[u];
            pxs += I_DIM;
        }

        const short (*hr)[72] = (const short(*)[72])(smem + H_OFF(t & 1));
        short (*hw)[72]       = (short(*)[72])(smem + H_OFF((t + 1) & 1));

        #pragma unroll
        for (int m = 0; m < 2; ++m){
            const int mt = m;

            // x-projection (bias rides in wih k=28 against x pad col = 1.0)
            f32x4 acc[4];
            {
                bf16x8 a = *(const bf16x8*)&xb[mt * 16 + col][quad * 8];
                #pragma unroll
                for (int nt = 0; nt < 4; ++nt)
                    acc[nt] = __builtin_amdgcn_mfma_f32_16x16x32_bf16(a, wih[nt], z4, 0, 0, 0);
            }
            // recurrence
            #pragma unroll
            for (int s = 0; s < 2; ++s){
                bf16x8 a = *(const bf16x8*)&hr[mt * 16 + col][s * 32 + quad * 8];
                #pragma unroll
                for (int nt = 0; nt < 4; ++nt)
                    acc[nt] = __builtin_amdgcn_mfma_f32_16x16x32_bf16(a, whh[s][nt], acc[nt], 0, 0, 0);
            }

            // activations: paired reciprocals, scalar form (no pk-pair moves).
            //   i = 1/DA, f = 1/DB via R1 = rcp(DA*DB); o,g via R2 = rcp(DG*DO);
            //   tanh(c) for adjacent rows via one rcp of the product.
            // Trans/elem: 5 exp2 + 2.5 rcp.
            // Overflow: gate pair products finite; tanh pair inf only when both
            // cells saturated -> rcp=0 -> tanh=1 (correct limit).
            float hv[4];
            #pragma unroll
            for (int p = 0; p < 2; ++p){
                const int r0 = 2 * p, r1 = 2 * p + 1;
                const float dA0 = 1.0f + __builtin_amdgcn_exp2f(acc[0][r0]);
                const float dA1 = 1.0f + __builtin_amdgcn_exp2f(acc[0][r1]);
                const float dB0 = 1.0f + __builtin_amdgcn_exp2f(acc[1][r0]);
                const float dB1 = 1.0f + __builtin_amdgcn_exp2f(acc[1][r1]);
                const float R10 = __builtin_amdgcn_rcpf(dA0 * dB0);
                const float R11 = __builtin_amdgcn_rcpf(dA1 * dB1);
                const float iv0 = R10 * dB0, fv0 = R10 * dA0;
                const float iv1 = R11 * dB1, fv1 = R11 * dA1;
                const float dG0 = 1.0f + __builtin_amdgcn_exp2f(acc[2][r0]);
                const float dG1 = 1.0f + __builtin_amdgcn_exp2f(acc[2][r1]);
                const float dO0 = 1.0f + __builtin_amdgcn_exp2f(acc[3][r0]);
                const float dO1 = 1.0f + __builtin_amdgcn_exp2f(acc[3][r1]);
                const float R20 = __builtin_amdgcn_rcpf(dG0 * dO0);
                const float R21 = __builtin_amdgcn_rcpf(dG1 * dO1);
                const float ov0 = R20 * dG0, ov1 = R21 * dG1;
                const float gv0 = 1.0f - 2.0f * (R20 * dO0);
                const float gv1 = 1.0f - 2.0f * (R21 * dO1);
                const float c0 = fv0 * cst[m][r0] + iv0 * gv0;
                const float c1 = fv1 * cst[m][r1] + iv1 * gv1;
                cst[m][r0] = c0; cst[m][r1] = c1;
                const float d50 = 1.0f + __builtin_amdgcn_exp2f(KG * c0);
                const float d51 = 1.0f + __builtin_amdgcn_exp2f(KG * c1);
                const float R5 = __builtin_amdgcn_rcpf(d50 * d51);
                const float t2 = 2.0f * R5;
                hv[r0] = ov0 * (1.0f - t2 * d51);
                hv[r1] = ov1 * (1.0f - t2 * d50);
            }
            // packed conversion, two b16 stores per pair (rows differ by 1)
            #pragma unroll
            for (int rp = 0; rp < 2; ++rp){
                uint32_t u = pack_bf16x2(hv[2 * rp], hv[2 * rp + 1]);
                hw[mt * 16 + quad * 4 + 2 * rp    ][jcol] = (short)(u & 0xffffu);
                hw[mt * 16 + quad * 4 + 2 * rp + 1][jcol] = (short)(u >> 16);
            }
        }
    }
    __syncthreads();

    // ---- output projection from final h (bf16, in h buffer 0) ----
    const short (*hfin)[72] = (const short(*)[72])(smem + H_OFF(0));
    for (int idx = tid; idx < BT * O_DIM; idx += NTHREADS){
        const int m = idx / O_DIM;
        const int o = idx - m * O_DIM;
        float s = bout_s[o];
        #pragma unroll 8
        for (int j = 0; j < H_DIM; ++j)
            s += bf2f(hfin[m][j]) * wout_t[j * O_DIM + o];
        out[(size_t)b0 * O_DIM + idx] = s;
    }
}

extern "C" void kernel_launch(void* const* d_in, const int* in_sizes, int n_in,
                              void* d_out, int out_size, void* d_ws, size_t ws_size,
                              hipStream_t stream) {
    const float* x     = (const float*)d_in[0];
    const float* W_ih  = (const float*)d_in[1];
    const float* W_hh  = (const float*)d_in[2];
    const float* b_ih  = (const float*)d_in[3];
    const float* b_hh  = (const float*)d_in[4];
    const float* W_out = (const float*)d_in[5];
    const float* b_out = (const float*)d_in[6];
    float* out = (float*)d_out;

    const int grid = 65536 / BT;   // 2048 blocks x 256 threads
    lstm_fused<<<grid, NTHREADS, 0, stream>>>(x, W_ih, W_hh, b_ih, b_hh, W_out, b_out, out);
}